// Round 3
// baseline (1913.299 us; speedup 1.0000x reference)
//
#include <hip/hip_runtime.h>
#include <hip/hip_bf16.h>

#define S_LEN 2048
#define DMODEL 512
#define NHEAD 8
#define DKH 64
#define FFDIM 2048
#define BATCH 2
#define NROWS (BATCH * S_LEN)  // 4096

using bf16 = __hip_bfloat16;
typedef __bf16 bf16x8 __attribute__((ext_vector_type(8)));
typedef float floatx4 __attribute__((ext_vector_type(4)));

// fp32 -> bf16 round-to-nearest-even, branch-free
__device__ inline unsigned short f2bf_bits(float f) {
    union { float f; unsigned u; } c; c.f = f;
    return (unsigned short)((c.u + 0x7FFFu + ((c.u >> 16) & 1u)) >> 16);
}

// Load an 8-element bf16 MFMA fragment from bf16 or fp32 memory.
__device__ inline bf16x8 load_frag(const bf16* p) {
    return *(const bf16x8*)p;
}
__device__ inline bf16x8 load_frag(const float* p) {
    const float4 a = *(const float4*)p;
    const float4 b = *(const float4*)(p + 4);
    union { unsigned short s[8]; bf16x8 v; } o;
    o.s[0] = f2bf_bits(a.x); o.s[1] = f2bf_bits(a.y);
    o.s[2] = f2bf_bits(a.z); o.s[3] = f2bf_bits(a.w);
    o.s[4] = f2bf_bits(b.x); o.s[5] = f2bf_bits(b.y);
    o.s[6] = f2bf_bits(b.z); o.s[7] = f2bf_bits(b.w);
    return o.v;
}

// ---------------------------------------------------------------------------
// GEMM: C[M,N] = A[M,K] @ W[N,K]^T + bias;  A,W fp32 or bf16; bias fp32;
// out fp32 and/or bf16. MFMA 16x16x32 bf16. Wave tile (16*WM)x(16*WN), 4 waves.
// Fragment layouts (HW-verified, learn_hip m89/m91/m92):
//   A operand: lane holds A[m = lane&15][k = (lane>>4)*8 + j], j=0..7 (contig)
//   B operand: lane holds B[k = (lane>>4)*8 + j][n = lane&15] = W[n][k] (contig)
//   C/D:       lane,reg holds C[row = (lane>>4)*4 + reg][col = lane&15]
// ---------------------------------------------------------------------------
template <typename TA, typename TW, int WM, int WN, bool RELU>
__launch_bounds__(256)
__global__ void gemm_bf16(const TA* __restrict__ A, const TW* __restrict__ W,
                          const float* __restrict__ bias,
                          float* __restrict__ outF, bf16* __restrict__ outB,
                          int M, int N, int K)
{
    const int wave = blockIdx.x * 4 + (threadIdx.x >> 6);
    const int lane = threadIdx.x & 63;
    const int ntiles = N / (16 * WN);
    const int wm = wave / ntiles;
    const int wn = wave - wm * ntiles;
    const int m0 = wm * (16 * WM);
    const int n0 = wn * (16 * WN);
    const int r = lane & 15;
    const int quad = lane >> 4;

    floatx4 acc[WM][WN];
#pragma unroll
    for (int i = 0; i < WM; i++)
#pragma unroll
        for (int j = 0; j < WN; j++)
#pragma unroll
            for (int e = 0; e < 4; e++) acc[i][j][e] = 0.0f;

    const TA* Abase = A + (size_t)(m0 + r) * K + quad * 8;
    const TW* Wbase = W + (size_t)(n0 + r) * K + quad * 8;

    for (int k0 = 0; k0 < K; k0 += 32) {
        bf16x8 af[WM], bfr[WN];
#pragma unroll
        for (int i = 0; i < WM; i++)
            af[i] = load_frag(Abase + (size_t)i * 16 * K + k0);
#pragma unroll
        for (int j = 0; j < WN; j++)
            bfr[j] = load_frag(Wbase + (size_t)j * 16 * K + k0);
#pragma unroll
        for (int i = 0; i < WM; i++)
#pragma unroll
            for (int j = 0; j < WN; j++)
                acc[i][j] = __builtin_amdgcn_mfma_f32_16x16x32_bf16(af[i], bfr[j], acc[i][j], 0, 0, 0);
    }

#pragma unroll
    for (int j = 0; j < WN; j++) {
        const int col = n0 + j * 16 + r;
        const float bv = bias ? bias[col] : 0.0f;
#pragma unroll
        for (int i = 0; i < WM; i++) {
            const int rowb = m0 + i * 16 + quad * 4;
#pragma unroll
            for (int rr = 0; rr < 4; rr++) {
                float v = acc[i][j][rr] + bv;
                if (RELU) v = fmaxf(v, 0.0f);
                const size_t idx = (size_t)(rowb + rr) * N + col;
                if (outF) outF[idx] = v;
                if (outB) outB[idx] = __float2bfloat16(v);
            }
        }
    }
}

// ---------------------------------------------------------------------------
// Flash-style attention, fp32 vector math, bf16 inputs (GEMM intermediates).
// One WG (256 thr) per (bh, 32 queries). Q,K,V bf16 [NROWS, DMODEL], head h at
// column offset h*64. Online softmax over key chunks of 64.
// ---------------------------------------------------------------------------
#define AT_ST 68  // LDS row stride (floats): 64 + 4 pad

union LD8 { uint4 u; bf16 h[8]; };

__launch_bounds__(256)
__global__ void attn_kernel(const bf16* __restrict__ Qh, const bf16* __restrict__ Kh,
                            const bf16* __restrict__ Vh,
                            float* __restrict__ outF, bf16* __restrict__ outB,
                            int causal)
{
    __shared__ float Qs[32][AT_ST];
    __shared__ float Ks[64][AT_ST];
    __shared__ float Vs[64][AT_ST];
    __shared__ float Ps[32][AT_ST];
    __shared__ float mrow[32], lrow[32], arow[32];

    const int t = threadIdx.x;
    const int bh = blockIdx.y;
    const int b = bh >> 3, h = bh & 7;
    const int q0 = blockIdx.x * 32;

    const bf16* Qb = Qh + (size_t)(b * S_LEN) * DMODEL + h * DKH;
    const bf16* Kb = Kh + (size_t)(b * S_LEN) * DMODEL + h * DKH;
    const bf16* Vb = Vh + (size_t)(b * S_LEN) * DMODEL + h * DKH;

    {   // load + convert + pre-scale Q tile (32 x 64), scale = 1/sqrt(64)
        const int r = t >> 3, c = (t & 7) * 8;   // 256 thr cover 32x64 in one pass
        LD8 ld; ld.u = *(const uint4*)(Qb + (size_t)(q0 + r) * DMODEL + c);
#pragma unroll
        for (int j = 0; j < 8; j++)
            Qs[r][c + j] = __bfloat162float(ld.h[j]) * 0.125f;
    }
    if (t < 32) { mrow[t] = -1e30f; lrow[t] = 0.0f; }

    float oacc[8];
#pragma unroll
    for (int i = 0; i < 8; i++) oacc[i] = 0.0f;

    const int qown = t >> 3;          // PV: owned query row 0..31
    const int d0 = (t & 7) * 8;       // PV: owned dim range
    const int qq = (t & 15) * 2;      // scores: 2 query rows
    const int kk = (t >> 4) * 4;      // scores: 4 keys

    const int nchunk = causal ? ((q0 >> 6) + 1) : (S_LEN / 64);

    for (int ch = 0; ch < nchunk; ch++) {
        const int kb = ch * 64;
        __syncthreads();  // protect Ks/Vs/Ps reuse across iterations
        {   // stage K,V chunk (64 x 64 each), bf16 -> fp32
            const int r = t >> 3, c = (t & 7) * 8;
#pragma unroll
            for (int it = 0; it < 2; it++) {
                const int rr = r + it * 32;
                LD8 lk; lk.u = *(const uint4*)(Kb + (size_t)(kb + rr) * DMODEL + c);
                LD8 lv; lv.u = *(const uint4*)(Vb + (size_t)(kb + rr) * DMODEL + c);
#pragma unroll
                for (int j = 0; j < 8; j++) {
                    Ks[rr][c + j] = __bfloat162float(lk.h[j]);
                    Vs[rr][c + j] = __bfloat162float(lv.h[j]);
                }
            }
        }
        __syncthreads();

        // scores: 2q x 4k register block per thread
        float sc[2][4];
#pragma unroll
        for (int i = 0; i < 2; i++)
#pragma unroll
            for (int j = 0; j < 4; j++) sc[i][j] = 0.0f;
        for (int d4 = 0; d4 < DKH; d4 += 4) {
            const float4 qa = *(float4*)&Qs[qq][d4];
            const float4 qc = *(float4*)&Qs[qq + 1][d4];
#pragma unroll
            for (int j = 0; j < 4; j++) {
                const float4 kv = *(float4*)&Ks[kk + j][d4];
                sc[0][j] += qa.x * kv.x + qa.y * kv.y + qa.z * kv.z + qa.w * kv.w;
                sc[1][j] += qc.x * kv.x + qc.y * kv.y + qc.z * kv.z + qc.w * kv.w;
            }
        }
        if (causal && (kb + 63 > q0)) {
#pragma unroll
            for (int i = 0; i < 2; i++)
#pragma unroll
                for (int j = 0; j < 4; j++)
                    if (kb + kk + j > q0 + qq + i) sc[i][j] = -1e30f;
        }
#pragma unroll
        for (int i = 0; i < 2; i++)
#pragma unroll
            for (int j = 0; j < 4; j++) Ps[qq + i][kk + j] = sc[i][j];
        __syncthreads();

        // online softmax row update (one thread per row)
        if (t < 32) {
            const float mold = mrow[t];
            float mx = mold;
            for (int k = 0; k < 64; k++) mx = fmaxf(mx, Ps[t][k]);
            const float alpha = __expf(mold - mx);
            float ls = 0.0f;
            for (int k = 0; k < 64; k++) {
                const float p = __expf(Ps[t][k] - mx);
                Ps[t][k] = p;
                ls += p;
            }
            mrow[t] = mx;
            lrow[t] = lrow[t] * alpha + ls;
            arow[t] = alpha;
        }
        __syncthreads();

        // PV accumulate: thread owns (qown, d0..d0+7) in registers
        const float al = arow[qown];
#pragma unroll
        for (int i = 0; i < 8; i++) oacc[i] *= al;
        for (int k = 0; k < 64; k++) {
            const float p = Ps[qown][k];
            const float4 v0 = *(float4*)&Vs[k][d0];
            const float4 v1 = *(float4*)&Vs[k][d0 + 4];
            oacc[0] += p * v0.x; oacc[1] += p * v0.y;
            oacc[2] += p * v0.z; oacc[3] += p * v0.w;
            oacc[4] += p * v1.x; oacc[5] += p * v1.y;
            oacc[6] += p * v1.z; oacc[7] += p * v1.w;
        }
    }

    const float inv_l = 1.0f / lrow[qown];
    const size_t ob = (size_t)(b * S_LEN + q0 + qown) * DMODEL + h * DKH + d0;
#pragma unroll
    for (int i = 0; i < 8; i++) {
        const float v = oacc[i] * inv_l;
        if (outF) outF[ob + i] = v;
        if (outB) outB[ob + i] = __float2bfloat16(v);
    }
}

// ---------------------------------------------------------------------------
// Fused residual + LayerNorm over D=512. One WG (256 thr) per row.
// x = xmain(fp32) + resF(fp32) or resB(bf16); g,b fp32;
// out -> bf16 intermediate and/or fp32 final.
// ---------------------------------------------------------------------------
__launch_bounds__(256)
__global__ void ln_kernel(const float* __restrict__ xmain,
                          const float* __restrict__ resF, const bf16* __restrict__ resB,
                          const float* __restrict__ g, const float* __restrict__ bb,
                          float* __restrict__ outF, bf16* __restrict__ outB)
{
    const int row = blockIdx.x;
    const int t = threadIdx.x;
    const size_t base = (size_t)row * DMODEL;

    float x0 = xmain[base + t];
    float x1 = xmain[base + t + 256];
    if (resF) { x0 += resF[base + t]; x1 += resF[base + t + 256]; }
    if (resB) { x0 += __bfloat162float(resB[base + t]); x1 += __bfloat162float(resB[base + t + 256]); }

    __shared__ float sred[4];
    float s = x0 + x1;
#pragma unroll
    for (int off = 32; off > 0; off >>= 1) s += __shfl_down(s, off);
    if ((t & 63) == 0) sred[t >> 6] = s;
    __syncthreads();
    const float mu = (sred[0] + sred[1] + sred[2] + sred[3]) * (1.0f / DMODEL);

    const float d0 = x0 - mu, d1 = x1 - mu;
    float sv = d0 * d0 + d1 * d1;
#pragma unroll
    for (int off = 32; off > 0; off >>= 1) sv += __shfl_down(sv, off);
    __syncthreads();  // everyone done reading sred
    if ((t & 63) == 0) sred[t >> 6] = sv;
    __syncthreads();
    const float var = (sred[0] + sred[1] + sred[2] + sred[3]) * (1.0f / DMODEL);
    const float rstd = rsqrtf(var + 1e-5f);

    const float y0 = d0 * rstd * g[t] + bb[t];
    const float y1 = d1 * rstd * g[t + 256] + bb[t + 256];
    if (outF) { outF[base + t] = y0; outF[base + t + 256] = y1; }
    if (outB) { outB[base + t] = __float2bfloat16(y0); outB[base + t + 256] = __float2bfloat16(y1); }
}

// ---------------------------------------------------------------------------
// Workspace layout (36 MB; this footprint ran to completion in round 2):
//   [ 0, 4)MB  q16   bf16 4096x512      } aliased by h16 (bf16 4096x2048,
//   [ 4, 8)MB  k16   bf16 4096x512      }  16 MB) once attention is done
//   [ 8,12)MB  v16   bf16 4096x512      }
//   [12,16)MB  a16   bf16 4096x512      }
//   [16,24)MB  tmp   fp32 4096x512  (pre-LN main term)
//   [24,28)MB  y16   bf16 (LN1 out)
//   [28,32)MB  ya16  bf16 (LN2 out)
//   [32,36)MB  ya2   bf16 (LN2' out)
// ---------------------------------------------------------------------------
extern "C" void kernel_launch(void* const* d_in, const int* in_sizes, int n_in,
                              void* d_out, int out_size, void* d_ws, size_t ws_size,
                              hipStream_t stream)
{
    // ALL inputs are float32 per the reference (jnp.float32 everywhere).
    const float* x_q       = (const float*)d_in[0];
    const float* x1        = (const float*)d_in[1];
    const float* x2        = (const float*)d_in[2];
    const float* sa_wq     = (const float*)d_in[3];
    const float* sa_bq     = (const float*)d_in[4];
    const float* sa_wk     = (const float*)d_in[5];
    const float* sa_bk     = (const float*)d_in[6];
    const float* sa_wv     = (const float*)d_in[7];
    const float* sa_bv     = (const float*)d_in[8];
    const float* ln1_g     = (const float*)d_in[9];
    const float* ln1_b     = (const float*)d_in[10];
    const float* mha_in_w  = (const float*)d_in[11];
    const float* mha_in_b  = (const float*)d_in[12];
    const float* mha_out_w = (const float*)d_in[13];
    const float* mha_out_b = (const float*)d_in[14];
    const float* ln2_g     = (const float*)d_in[15];
    const float* ln2_b     = (const float*)d_in[16];
    const float* ffn_w1    = (const float*)d_in[17];
    const float* ffn_b1    = (const float*)d_in[18];
    const float* ffn_w2    = (const float*)d_in[19];
    const float* ffn_b2    = (const float*)d_in[20];
    const float* ln3_g     = (const float*)d_in[21];
    const float* ln3_b     = (const float*)d_in[22];

    char* ws = (char*)d_ws;
    const size_t MB = 1024 * 1024;
    bf16*  q16  = (bf16*)(ws + 0 * MB);
    bf16*  k16  = (bf16*)(ws + 4 * MB);
    bf16*  v16  = (bf16*)(ws + 8 * MB);
    bf16*  a16  = (bf16*)(ws + 12 * MB);
    float* tmp  = (float*)(ws + 16 * MB);
    bf16*  y16  = (bf16*)(ws + 24 * MB);
    bf16*  ya16 = (bf16*)(ws + 28 * MB);
    bf16*  ya2  = (bf16*)(ws + 32 * MB);
    bf16*  h16  = (bf16*)(ws + 0 * MB);   // aliases q16..a16 (dead by FFN)

    const dim3 blk(256);
    const int GB512 = (NROWS / 64) * (DMODEL / 32) / 4;    // 256 blocks (WM=4,WN=2)
    const int GBFF  = (NROWS / 64) * (FFDIM / 64) / 4;     // 512 blocks (WM=4,WN=4)
    const dim3 agrid(S_LEN / 32, BATCH * NHEAD);

    // ---- self attention (causal, no out-proj) ----
    gemm_bf16<float, float, 4, 2, false><<<GB512, blk, 0, stream>>>(x_q, sa_wq, sa_bq, nullptr, q16, NROWS, DMODEL, DMODEL);
    gemm_bf16<float, float, 4, 2, false><<<GB512, blk, 0, stream>>>(x_q, sa_wk, sa_bk, nullptr, k16, NROWS, DMODEL, DMODEL);
    gemm_bf16<float, float, 4, 2, false><<<GB512, blk, 0, stream>>>(x_q, sa_wv, sa_bv, nullptr, v16, NROWS, DMODEL, DMODEL);
    attn_kernel<<<agrid, blk, 0, stream>>>(q16, k16, v16, tmp, nullptr, 1);
    ln_kernel<<<NROWS, blk, 0, stream>>>(tmp, x_q, nullptr, ln1_g, ln1_b, nullptr, y16);

    // ---- cross attention 1: q from y, k/v from x1 ----
    gemm_bf16<bf16,  float, 4, 2, false><<<GB512, blk, 0, stream>>>(y16, mha_in_w, mha_in_b, nullptr, q16, NROWS, DMODEL, DMODEL);
    gemm_bf16<float, float, 4, 2, false><<<GB512, blk, 0, stream>>>(x1, mha_in_w + (size_t)DMODEL * DMODEL, mha_in_b + DMODEL, nullptr, k16, NROWS, DMODEL, DMODEL);
    gemm_bf16<float, float, 4, 2, false><<<GB512, blk, 0, stream>>>(x1, mha_in_w + (size_t)2 * DMODEL * DMODEL, mha_in_b + 2 * DMODEL, nullptr, v16, NROWS, DMODEL, DMODEL);
    attn_kernel<<<agrid, blk, 0, stream>>>(q16, k16, v16, nullptr, a16, 0);
    gemm_bf16<bf16,  float, 4, 2, false><<<GB512, blk, 0, stream>>>(a16, mha_out_w, mha_out_b, tmp, nullptr, NROWS, DMODEL, DMODEL);
    ln_kernel<<<NROWS, blk, 0, stream>>>(tmp, nullptr, y16, ln2_g, ln2_b, nullptr, ya16);

    // ---- cross attention 2: q from yattn, k/v from x2 ----
    gemm_bf16<bf16,  float, 4, 2, false><<<GB512, blk, 0, stream>>>(ya16, mha_in_w, mha_in_b, nullptr, q16, NROWS, DMODEL, DMODEL);
    gemm_bf16<float, float, 4, 2, false><<<GB512, blk, 0, stream>>>(x2, mha_in_w + (size_t)DMODEL * DMODEL, mha_in_b + DMODEL, nullptr, k16, NROWS, DMODEL, DMODEL);
    gemm_bf16<float, float, 4, 2, false><<<GB512, blk, 0, stream>>>(x2, mha_in_w + (size_t)2 * DMODEL * DMODEL, mha_in_b + 2 * DMODEL, nullptr, v16, NROWS, DMODEL, DMODEL);
    attn_kernel<<<agrid, blk, 0, stream>>>(q16, k16, v16, nullptr, a16, 0);
    gemm_bf16<bf16,  float, 4, 2, false><<<GB512, blk, 0, stream>>>(a16, mha_out_w, mha_out_b, tmp, nullptr, NROWS, DMODEL, DMODEL);
    ln_kernel<<<NROWS, blk, 0, stream>>>(tmp, nullptr, ya16, ln2_g, ln2_b, nullptr, ya2);

    // ---- FFN ----
    gemm_bf16<bf16, float, 4, 4, true ><<<GBFF, blk, 0, stream>>>(ya2, ffn_w1, ffn_b1, nullptr, h16, NROWS, FFDIM, DMODEL);
    gemm_bf16<bf16, float, 4, 2, false><<<GB512, blk, 0, stream>>>(h16, ffn_w2, ffn_b2, tmp, nullptr, NROWS, DMODEL, FFDIM);
    ln_kernel<<<NROWS, blk, 0, stream>>>(tmp, nullptr, ya2, ln3_g, ln3_b, (float*)d_out, nullptr);
}

// Round 4
// 733.398 us; speedup vs baseline: 2.6088x; 2.6088x over previous
//
#include <hip/hip_runtime.h>
#include <hip/hip_bf16.h>

#define S_LEN 2048
#define DMODEL 512
#define NHEAD 8
#define DKH 64
#define FFDIM 2048
#define BATCH 2
#define NROWS (BATCH * S_LEN)  // 4096

using bf16 = __hip_bfloat16;
typedef __bf16 bf16x8 __attribute__((ext_vector_type(8)));
typedef float floatx4 __attribute__((ext_vector_type(4)));

// fp32 -> bf16 round-to-nearest-even, branch-free
__device__ inline unsigned short f2bf_bits(float f) {
    union { float f; unsigned u; } c; c.f = f;
    return (unsigned short)((c.u + 0x7FFFu + ((c.u >> 16) & 1u)) >> 16);
}
__device__ inline unsigned pack2bf(float a, float b) {
    return (unsigned)f2bf_bits(a) | ((unsigned)f2bf_bits(b) << 16);
}

// Load an 8-element bf16 MFMA fragment from bf16 or fp32 memory.
__device__ inline bf16x8 load_frag(const bf16* p) {
    return *(const bf16x8*)p;
}
__device__ inline bf16x8 load_frag(const float* p) {
    const float4 a = *(const float4*)p;
    const float4 b = *(const float4*)(p + 4);
    union { unsigned short s[8]; bf16x8 v; } o;
    o.s[0] = f2bf_bits(a.x); o.s[1] = f2bf_bits(a.y);
    o.s[2] = f2bf_bits(a.z); o.s[3] = f2bf_bits(a.w);
    o.s[4] = f2bf_bits(b.x); o.s[5] = f2bf_bits(b.y);
    o.s[6] = f2bf_bits(b.z); o.s[7] = f2bf_bits(b.w);
    return o.v;
}

// ---------------------------------------------------------------------------
// GEMM: C[M,N] = A[M,K] @ W[N,K]^T + bias;  A,W fp32 or bf16; bias fp32;
// out fp32 and/or bf16. MFMA 16x16x32 bf16. Wave tile (16*WM)x(16*WN), 4 waves.
// Fragment layouts (HW-verified, learn_hip m89/m91/m92):
//   A operand: lane holds A[m = lane&15][k = (lane>>4)*8 + j], j=0..7 (contig)
//   B operand: lane holds B[k = (lane>>4)*8 + j][n = lane&15] = W[n][k] (contig)
//   C/D:       lane,reg holds C[row = (lane>>4)*4 + reg][col = lane&15]
// ---------------------------------------------------------------------------
template <typename TA, typename TW, int WM, int WN, bool RELU>
__launch_bounds__(256)
__global__ void gemm_bf16(const TA* __restrict__ A, const TW* __restrict__ W,
                          const float* __restrict__ bias,
                          float* __restrict__ outF, bf16* __restrict__ outB,
                          int M, int N, int K)
{
    const int wave = blockIdx.x * 4 + (threadIdx.x >> 6);
    const int lane = threadIdx.x & 63;
    const int ntiles = N / (16 * WN);
    const int wm = wave / ntiles;
    const int wn = wave - wm * ntiles;
    const int m0 = wm * (16 * WM);
    const int n0 = wn * (16 * WN);
    const int r = lane & 15;
    const int quad = lane >> 4;

    floatx4 acc[WM][WN];
#pragma unroll
    for (int i = 0; i < WM; i++)
#pragma unroll
        for (int j = 0; j < WN; j++)
#pragma unroll
            for (int e = 0; e < 4; e++) acc[i][j][e] = 0.0f;

    const TA* Abase = A + (size_t)(m0 + r) * K + quad * 8;
    const TW* Wbase = W + (size_t)(n0 + r) * K + quad * 8;

    for (int k0 = 0; k0 < K; k0 += 32) {
        bf16x8 af[WM], bfr[WN];
#pragma unroll
        for (int i = 0; i < WM; i++)
            af[i] = load_frag(Abase + (size_t)i * 16 * K + k0);
#pragma unroll
        for (int j = 0; j < WN; j++)
            bfr[j] = load_frag(Wbase + (size_t)j * 16 * K + k0);
#pragma unroll
        for (int i = 0; i < WM; i++)
#pragma unroll
            for (int j = 0; j < WN; j++)
                acc[i][j] = __builtin_amdgcn_mfma_f32_16x16x32_bf16(af[i], bfr[j], acc[i][j], 0, 0, 0);
    }

#pragma unroll
    for (int j = 0; j < WN; j++) {
        const int col = n0 + j * 16 + r;
        const float bv = bias ? bias[col] : 0.0f;
#pragma unroll
        for (int i = 0; i < WM; i++) {
            const int rowb = m0 + i * 16 + quad * 4;
#pragma unroll
            for (int rr = 0; rr < 4; rr++) {
                float v = acc[i][j][rr] + bv;
                if (RELU) v = fmaxf(v, 0.0f);
                const size_t idx = (size_t)(rowb + rr) * N + col;
                if (outF) outF[idx] = v;
                if (outB) outB[idx] = __float2bfloat16(v);
            }
        }
    }
}

// ---------------------------------------------------------------------------
// MFMA flash attention (bf16 QK^T and PV on matrix cores, fp32 softmax).
// One WG (256 thr, 4 waves) per (bh, 64-query tile); wave w owns 16 queries.
// Key chunks of 64 staged in LDS: Ks row-major (QK A-operand), Vt transposed
// (PV B-operand). S^T = K·Q^T so the query index lands in lane&15 of the
// C-layout -> online-softmax stats (m,l) are lane-resident; reductions are
// 2x shfl_xor. P goes through a per-wave LDS region (packed bf16 b64 writes,
// b128 A-fragment reads) to convert C-layout -> A-operand layout (m120).
// LDS stride 72 elems (144B) keeps every b128 row access 16B-aligned.
// ---------------------------------------------------------------------------
__launch_bounds__(256)
__global__ void attn_mfma(const bf16* __restrict__ Qh, const bf16* __restrict__ Kh,
                          const bf16* __restrict__ Vh,
                          float* __restrict__ outF, bf16* __restrict__ outB,
                          int causal)
{
    __shared__ alignas(16) bf16 Ks[64][72];      // [key][d]
    __shared__ alignas(16) bf16 Vt[64][72];      // [d][key]
    __shared__ alignas(16) bf16 Ps[4][16][72];   // per-wave [q][key]

    const int t = threadIdx.x;
    const int w = t >> 6;
    const int lane = t & 63;
    const int r16 = lane & 15;
    const int quad = lane >> 4;
    const int bh = blockIdx.y;
    const int b = bh >> 3, h = bh & 7;
    const int q0 = blockIdx.x * 64;
    const size_t rowbase = (size_t)b * S_LEN;
    const int hoff = h * DKH;

    // Persistent Q fragments (B-operand): lane holds Q[q=r16][d=32*t2+8*quad+j]
    bf16x8 qf[2];
    {
        const bf16* qp = Qh + (rowbase + q0 + 16 * w + r16) * DMODEL + hoff + 8 * quad;
        qf[0] = *(const bf16x8*)(qp);
        qf[1] = *(const bf16x8*)(qp + 32);
    }

    floatx4 o[4];
#pragma unroll
    for (int dt = 0; dt < 4; dt++)
#pragma unroll
        for (int e = 0; e < 4; e++) o[dt][e] = 0.0f;
    float m = -3e38f, l = 0.0f;

    const int nchunk = causal ? (q0 / 64 + 1) : (S_LEN / 64);
    const int rr0 = t >> 3;          // staging: rows 0..31 (+32 second pass)
    const int cc = (t & 7) * 8;      // staging: col group

    for (int ch = 0; ch < nchunk; ch++) {
        const int kb = ch * 64;
        __syncthreads();  // protect Ks/Vt reuse from previous chunk's readers
        {
#pragma unroll
            for (int p = 0; p < 2; p++) {
                const int row = rr0 + 32 * p;
                const size_t goff = (rowbase + kb + row) * DMODEL + hoff + cc;
                *(uint4*)&Ks[row][cc] = *(const uint4*)(Kh + goff);
                union { uint4 u; bf16 hh[8]; } vv;
                vv.u = *(const uint4*)(Vh + goff);
#pragma unroll
                for (int j = 0; j < 8; j++) Vt[cc + j][row] = vv.hh[j];
            }
        }
        __syncthreads();

        // ---- S^T = K . Q^T : 4 key-subtiles x (2 MFMAs over d) ----
        floatx4 sacc[4];
#pragma unroll
        for (int i = 0; i < 4; i++)
#pragma unroll
            for (int e = 0; e < 4; e++) sacc[i][e] = 0.0f;
#pragma unroll
        for (int t2 = 0; t2 < 2; t2++) {
            bf16x8 kf[4];
#pragma unroll
            for (int i = 0; i < 4; i++)
                kf[i] = *(const bf16x8*)&Ks[16 * i + r16][32 * t2 + 8 * quad];
#pragma unroll
            for (int i = 0; i < 4; i++)
                sacc[i] = __builtin_amdgcn_mfma_f32_16x16x32_bf16(kf[i], qf[t2], sacc[i], 0, 0, 0);
        }

        // ---- scale + causal mask; chunk max ----
        const int qg = q0 + 16 * w + r16;      // this lane's query (column of S^T)
        float mc = -3e38f;
#pragma unroll
        for (int i = 0; i < 4; i++)
#pragma unroll
            for (int e = 0; e < 4; e++) {
                float sv = sacc[i][e] * 0.125f;
                if (causal && (kb + 16 * i + 4 * quad + e > qg)) sv = -3e38f;
                sacc[i][e] = sv;
                mc = fmaxf(mc, sv);
            }
        mc = fmaxf(mc, __shfl_xor(mc, 16, 64));
        mc = fmaxf(mc, __shfl_xor(mc, 32, 64));
        const float mn = fmaxf(m, mc);
        const float alpha = __expf(m - mn);
        m = mn;

        // ---- p = exp(s - m); chunk sum; write P (packed bf16) ----
        float lc = 0.0f;
#pragma unroll
        for (int i = 0; i < 4; i++) {
            float p0 = __expf(sacc[i][0] - mn);
            float p1 = __expf(sacc[i][1] - mn);
            float p2 = __expf(sacc[i][2] - mn);
            float p3 = __expf(sacc[i][3] - mn);
            lc += (p0 + p1) + (p2 + p3);
            uint2 pw;
            pw.x = pack2bf(p0, p1);
            pw.y = pack2bf(p2, p3);
            *(uint2*)&Ps[w][r16][16 * i + 4 * quad] = pw;
        }
        lc += __shfl_xor(lc, 16, 64);
        lc += __shfl_xor(lc, 32, 64);
        l = l * alpha + lc;

        // ---- rescale O by alpha of its C-layout rows (q = 4*quad+reg) ----
        float aq[4];
#pragma unroll
        for (int e = 0; e < 4; e++) aq[e] = __shfl(alpha, 4 * quad + e, 64);
#pragma unroll
        for (int dt = 0; dt < 4; dt++)
#pragma unroll
            for (int e = 0; e < 4; e++) o[dt][e] *= aq[e];

        // ---- O += P . V  (A = P from LDS, B = Vt rows) ----
#pragma unroll
        for (int t2 = 0; t2 < 2; t2++) {
            const bf16x8 pf = *(const bf16x8*)&Ps[w][r16][32 * t2 + 8 * quad];
#pragma unroll
            for (int dt = 0; dt < 4; dt++) {
                const bf16x8 vf = *(const bf16x8*)&Vt[16 * dt + r16][32 * t2 + 8 * quad];
                o[dt] = __builtin_amdgcn_mfma_f32_16x16x32_bf16(pf, vf, o[dt], 0, 0, 0);
            }
        }
    }

    // ---- finalize: divide by l, store O (C-layout: row q=4*quad+reg, col d=r16)
    float linv[4];
#pragma unroll
    for (int e = 0; e < 4; e++) linv[e] = 1.0f / __shfl(l, 4 * quad + e, 64);
#pragma unroll
    for (int dt = 0; dt < 4; dt++)
#pragma unroll
        for (int e = 0; e < 4; e++) {
            const float v = o[dt][e] * linv[e];
            const size_t idx = (rowbase + q0 + 16 * w + 4 * quad + e) * DMODEL
                             + hoff + 16 * dt + r16;
            if (outF) outF[idx] = v;
            if (outB) outB[idx] = __float2bfloat16(v);
        }
}

// ---------------------------------------------------------------------------
// Fused residual + LayerNorm over D=512. One WG (256 thr) per row.
// ---------------------------------------------------------------------------
__launch_bounds__(256)
__global__ void ln_kernel(const float* __restrict__ xmain,
                          const float* __restrict__ resF, const bf16* __restrict__ resB,
                          const float* __restrict__ g, const float* __restrict__ bb,
                          float* __restrict__ outF, bf16* __restrict__ outB)
{
    const int row = blockIdx.x;
    const int t = threadIdx.x;
    const size_t base = (size_t)row * DMODEL;

    float x0 = xmain[base + t];
    float x1 = xmain[base + t + 256];
    if (resF) { x0 += resF[base + t]; x1 += resF[base + t + 256]; }
    if (resB) { x0 += __bfloat162float(resB[base + t]); x1 += __bfloat162float(resB[base + t + 256]); }

    __shared__ float sred[4];
    float s = x0 + x1;
#pragma unroll
    for (int off = 32; off > 0; off >>= 1) s += __shfl_down(s, off);
    if ((t & 63) == 0) sred[t >> 6] = s;
    __syncthreads();
    const float mu = (sred[0] + sred[1] + sred[2] + sred[3]) * (1.0f / DMODEL);

    const float d0 = x0 - mu, d1 = x1 - mu;
    float sv = d0 * d0 + d1 * d1;
#pragma unroll
    for (int off = 32; off > 0; off >>= 1) sv += __shfl_down(sv, off);
    __syncthreads();  // everyone done reading sred
    if ((t & 63) == 0) sred[t >> 6] = sv;
    __syncthreads();
    const float var = (sred[0] + sred[1] + sred[2] + sred[3]) * (1.0f / DMODEL);
    const float rstd = rsqrtf(var + 1e-5f);

    const float y0 = d0 * rstd * g[t] + bb[t];
    const float y1 = d1 * rstd * g[t + 256] + bb[t + 256];
    if (outF) { outF[base + t] = y0; outF[base + t + 256] = y1; }
    if (outB) { outB[base + t] = __float2bfloat16(y0); outB[base + t + 256] = __float2bfloat16(y1); }
}

// ---------------------------------------------------------------------------
// Workspace layout (36 MB):
//   [ 0, 4)MB  q16   bf16 4096x512      } aliased by h16 (bf16 4096x2048,
//   [ 4, 8)MB  k16   bf16 4096x512      }  16 MB) once attention is done
//   [ 8,12)MB  v16   bf16 4096x512      }
//   [12,16)MB  a16   bf16 4096x512      }
//   [16,24)MB  tmp   fp32 4096x512  (pre-LN main term)
//   [24,28)MB  y16   bf16 (LN1 out)
//   [28,32)MB  ya16  bf16 (LN2 out)
//   [32,36)MB  ya2   bf16 (LN2' out)
// ---------------------------------------------------------------------------
extern "C" void kernel_launch(void* const* d_in, const int* in_sizes, int n_in,
                              void* d_out, int out_size, void* d_ws, size_t ws_size,
                              hipStream_t stream)
{
    // ALL inputs are float32 per the reference (jnp.float32 everywhere).
    const float* x_q       = (const float*)d_in[0];
    const float* x1        = (const float*)d_in[1];
    const float* x2        = (const float*)d_in[2];
    const float* sa_wq     = (const float*)d_in[3];
    const float* sa_bq     = (const float*)d_in[4];
    const float* sa_wk     = (const float*)d_in[5];
    const float* sa_bk     = (const float*)d_in[6];
    const float* sa_wv     = (const float*)d_in[7];
    const float* sa_bv     = (const float*)d_in[8];
    const float* ln1_g     = (const float*)d_in[9];
    const float* ln1_b     = (const float*)d_in[10];
    const float* mha_in_w  = (const float*)d_in[11];
    const float* mha_in_b  = (const float*)d_in[12];
    const float* mha_out_w = (const float*)d_in[13];
    const float* mha_out_b = (const float*)d_in[14];
    const float* ln2_g     = (const float*)d_in[15];
    const float* ln2_b     = (const float*)d_in[16];
    const float* ffn_w1    = (const float*)d_in[17];
    const float* ffn_b1    = (const float*)d_in[18];
    const float* ffn_w2    = (const float*)d_in[19];
    const float* ffn_b2    = (const float*)d_in[20];
    const float* ln3_g     = (const float*)d_in[21];
    const float* ln3_b     = (const float*)d_in[22];

    char* ws = (char*)d_ws;
    const size_t MB = 1024 * 1024;
    bf16*  q16  = (bf16*)(ws + 0 * MB);
    bf16*  k16  = (bf16*)(ws + 4 * MB);
    bf16*  v16  = (bf16*)(ws + 8 * MB);
    bf16*  a16  = (bf16*)(ws + 12 * MB);
    float* tmp  = (float*)(ws + 16 * MB);
    bf16*  y16  = (bf16*)(ws + 24 * MB);
    bf16*  ya16 = (bf16*)(ws + 28 * MB);
    bf16*  ya2  = (bf16*)(ws + 32 * MB);
    bf16*  h16  = (bf16*)(ws + 0 * MB);   // aliases q16..a16 (dead by FFN)

    const dim3 blk(256);
    const int GB512 = (NROWS / 64) * (DMODEL / 32) / 4;    // 256 blocks (WM=4,WN=2)
    const int GBFF  = (NROWS / 64) * (FFDIM / 64) / 4;     // 512 blocks (WM=4,WN=4)
    const dim3 agrid(S_LEN / 64, BATCH * NHEAD);           // 32 x 16 = 512 WGs

    // ---- self attention (causal, no out-proj) ----
    gemm_bf16<float, float, 4, 2, false><<<GB512, blk, 0, stream>>>(x_q, sa_wq, sa_bq, nullptr, q16, NROWS, DMODEL, DMODEL);
    gemm_bf16<float, float, 4, 2, false><<<GB512, blk, 0, stream>>>(x_q, sa_wk, sa_bk, nullptr, k16, NROWS, DMODEL, DMODEL);
    gemm_bf16<float, float, 4, 2, false><<<GB512, blk, 0, stream>>>(x_q, sa_wv, sa_bv, nullptr, v16, NROWS, DMODEL, DMODEL);
    attn_mfma<<<agrid, blk, 0, stream>>>(q16, k16, v16, tmp, nullptr, 1);
    ln_kernel<<<NROWS, blk, 0, stream>>>(tmp, x_q, nullptr, ln1_g, ln1_b, nullptr, y16);

    // ---- cross attention 1: q from y, k/v from x1 ----
    gemm_bf16<bf16,  float, 4, 2, false><<<GB512, blk, 0, stream>>>(y16, mha_in_w, mha_in_b, nullptr, q16, NROWS, DMODEL, DMODEL);
    gemm_bf16<float, float, 4, 2, false><<<GB512, blk, 0, stream>>>(x1, mha_in_w + (size_t)DMODEL * DMODEL, mha_in_b + DMODEL, nullptr, k16, NROWS, DMODEL, DMODEL);
    gemm_bf16<float, float, 4, 2, false><<<GB512, blk, 0, stream>>>(x1, mha_in_w + (size_t)2 * DMODEL * DMODEL, mha_in_b + 2 * DMODEL, nullptr, v16, NROWS, DMODEL, DMODEL);
    attn_mfma<<<agrid, blk, 0, stream>>>(q16, k16, v16, nullptr, a16, 0);
    gemm_bf16<bf16,  float, 4, 2, false><<<GB512, blk, 0, stream>>>(a16, mha_out_w, mha_out_b, tmp, nullptr, NROWS, DMODEL, DMODEL);
    ln_kernel<<<NROWS, blk, 0, stream>>>(tmp, nullptr, y16, ln2_g, ln2_b, nullptr, ya16);

    // ---- cross attention 2: q from yattn, k/v from x2 ----
    gemm_bf16<bf16,  float, 4, 2, false><<<GB512, blk, 0, stream>>>(ya16, mha_in_w, mha_in_b, nullptr, q16, NROWS, DMODEL, DMODEL);
    gemm_bf16<float, float, 4, 2, false><<<GB512, blk, 0, stream>>>(x2, mha_in_w + (size_t)DMODEL * DMODEL, mha_in_b + DMODEL, nullptr, k16, NROWS, DMODEL, DMODEL);
    gemm_bf16<float, float, 4, 2, false><<<GB512, blk, 0, stream>>>(x2, mha_in_w + (size_t)2 * DMODEL * DMODEL, mha_in_b + 2 * DMODEL, nullptr, v16, NROWS, DMODEL, DMODEL);
    attn_mfma<<<agrid, blk, 0, stream>>>(q16, k16, v16, nullptr, a16, 0);
    gemm_bf16<bf16,  float, 4, 2, false><<<GB512, blk, 0, stream>>>(a16, mha_out_w, mha_out_b, tmp, nullptr, NROWS, DMODEL, DMODEL);
    ln_kernel<<<NROWS, blk, 0, stream>>>(tmp, nullptr, ya16, ln2_g, ln2_b, nullptr, ya2);

    // ---- FFN ----
    gemm_bf16<bf16, float, 4, 4, true ><<<GBFF, blk, 0, stream>>>(ya2, ffn_w1, ffn_b1, nullptr, h16, NROWS, FFDIM, DMODEL);
    gemm_bf16<bf16, float, 4, 2, false><<<GB512, blk, 0, stream>>>(h16, ffn_w2, ffn_b2, tmp, nullptr, NROWS, DMODEL, FFDIM);
    ln_kernel<<<NROWS, blk, 0, stream>>>(tmp, nullptr, ya2, ln3_g, ln3_b, (float*)d_out, nullptr);
}

// Round 5
// 566.739 us; speedup vs baseline: 3.3760x; 1.2941x over previous
//
#include <hip/hip_runtime.h>
#include <hip/hip_bf16.h>

#define S_LEN 2048
#define DMODEL 512
#define NHEAD 8
#define DKH 64
#define FFDIM 2048
#define BATCH 2
#define NROWS (BATCH * S_LEN)  // 4096

using bf16 = __hip_bfloat16;
typedef __bf16 bf16x8 __attribute__((ext_vector_type(8)));
typedef float floatx4 __attribute__((ext_vector_type(4)));

// fp32 -> bf16 round-to-nearest-even, branch-free
__device__ inline unsigned short f2bf_bits(float f) {
    union { float f; unsigned u; } c; c.f = f;
    return (unsigned short)((c.u + 0x7FFFu + ((c.u >> 16) & 1u)) >> 16);
}
__device__ inline unsigned pack2bf(float a, float b) {
    return (unsigned)f2bf_bits(a) | ((unsigned)f2bf_bits(b) << 16);
}

// async global->LDS, 16 bytes/lane. LDS dest is wave-uniform base + lane*16
// (m104/m108) — caller must pass lds = base + lane*8 bf16 elems.
__device__ __forceinline__ void gload_lds16(const bf16* g, bf16* l) {
    __builtin_amdgcn_global_load_lds(
        (const __attribute__((address_space(1))) void*)(const void*)g,
        (__attribute__((address_space(3))) void*)(void*)l, 16, 0, 0);
}

// ---------------------------------------------------------------------------
// fp32 -> bf16 bulk convert, up to 12 segments in one dispatch.
// ---------------------------------------------------------------------------
struct CvtSeg { const float* s; bf16* d; int n4; };
struct CvtDesc { CvtSeg seg[12]; };

__launch_bounds__(256)
__global__ void cvt_f32_bf16(CvtDesc desc) {
    const CvtSeg sg = desc.seg[blockIdx.y];
    const int stride = gridDim.x * 256;
    for (int i = blockIdx.x * 256 + threadIdx.x; i < sg.n4; i += stride) {
        const float4 v = ((const float4*)sg.s)[i];
        uint2 o;
        o.x = pack2bf(v.x, v.y);
        o.y = pack2bf(v.z, v.w);
        ((uint2*)sg.d)[i] = o;
    }
}

// ---------------------------------------------------------------------------
// m97-style GEMM: C[M,N] = A[M,K] @ W[N,K]^T + bias. A,W bf16; bias fp32.
// BMxBN tile, BK=32, 4 waves (2x2), async global_load_lds staging,
// ds_read_b128 fragments, MFMA 16x16x32. M = NROWS fixed.
// Fragment layouts (HW-verified m89/m91):
//   A: lane holds A[m=lane&15][k=(lane>>4)*8+j] (contig 16B)
//   B: lane holds W[n=lane&15][k=(lane>>4)*8+j] (contig 16B)
//   C/D: row = (lane>>4)*4+reg, col = lane&15
// ---------------------------------------------------------------------------
template <int BM, int BN, bool RELU>
__launch_bounds__(256)
__global__ void gemm_lds(const bf16* __restrict__ A, const bf16* __restrict__ W,
                         const float* __restrict__ bias,
                         float* __restrict__ outF, bf16* __restrict__ outB,
                         int N, int K)
{
    constexpr int WR = BM / 32;   // A-frags per wave
    constexpr int WC = BN / 32;   // B-frags per wave
    constexpr int SA = BM / 16;   // 16-row staging segments for A
    constexpr int ST = SA + BN / 16;

    __shared__ alignas(16) bf16 As[BM * 32];
    __shared__ alignas(16) bf16 Bs[BN * 32];

    const int t = threadIdx.x;
    const int w = t >> 6;
    const int lane = t & 63;
    const int r16 = lane & 15;
    const int quad = lane >> 4;
    const int wm = w >> 1, wn = w & 1;
    const int m0 = blockIdx.x * BM;
    const int n0 = blockIdx.y * BN;

    floatx4 acc[WR][WC];
#pragma unroll
    for (int i = 0; i < WR; i++)
#pragma unroll
        for (int j = 0; j < WC; j++)
#pragma unroll
            for (int e = 0; e < 4; e++) acc[i][j][e] = 0.0f;

    // per-lane staging offsets: 4 lanes cover one 32-elem row (16B each)
    const int srow = lane >> 2;          // 0..15 within segment
    const int scol = (lane & 3) * 8;     // elem offset

    const bf16* aLd = As + (size_t)((wm * (BM / 2)) + r16) * 32 + quad * 8;
    const bf16* bLd = Bs + (size_t)((wn * (BN / 2)) + r16) * 32 + quad * 8;

    for (int k0 = 0; k0 < K; k0 += 32) {
        __syncthreads();   // previous iteration's ds_reads done -> safe to overwrite
#pragma unroll
        for (int s = 0; s < ST; s += 4) {
            const int sg = s + w;
            if (sg < ST) {
                const bf16* src = (sg < SA)
                    ? (A + ((size_t)(m0 + 16 * sg)) * K)
                    : (W + ((size_t)(n0 + 16 * (sg - SA))) * K);
                bf16* dst = (sg < SA) ? (As + sg * 16 * 32)
                                      : (Bs + (sg - SA) * 16 * 32);
                gload_lds16(src + (size_t)srow * K + k0 + scol, dst + lane * 8);
            }
        }
        __syncthreads();   // drains vmcnt(0): staged tile visible

        bf16x8 af[WR], bfr[WC];
#pragma unroll
        for (int i = 0; i < WR; i++)
            af[i] = *(const bf16x8*)(aLd + i * 16 * 32);
#pragma unroll
        for (int j = 0; j < WC; j++)
            bfr[j] = *(const bf16x8*)(bLd + j * 16 * 32);
#pragma unroll
        for (int i = 0; i < WR; i++)
#pragma unroll
            for (int j = 0; j < WC; j++)
                acc[i][j] = __builtin_amdgcn_mfma_f32_16x16x32_bf16(af[i], bfr[j], acc[i][j], 0, 0, 0);
    }

#pragma unroll
    for (int j = 0; j < WC; j++) {
        const int col = n0 + wn * (BN / 2) + 16 * j + r16;
        const float bv = bias ? bias[col] : 0.0f;
#pragma unroll
        for (int i = 0; i < WR; i++) {
            const int rowb = m0 + wm * (BM / 2) + 16 * i + 4 * quad;
#pragma unroll
            for (int e = 0; e < 4; e++) {
                float v = acc[i][j][e] + bv;
                if (RELU) v = fmaxf(v, 0.0f);
                const size_t idx = (size_t)(rowb + e) * N + col;
                if (outF) outF[idx] = v;
                if (outB) outB[idx] = __float2bfloat16(v);
            }
        }
    }
}

// ---------------------------------------------------------------------------
// MFMA flash attention (unchanged from round 4: 89 us/call, round-6 target).
// ---------------------------------------------------------------------------
__launch_bounds__(256)
__global__ void attn_mfma(const bf16* __restrict__ Qh, const bf16* __restrict__ Kh,
                          const bf16* __restrict__ Vh,
                          float* __restrict__ outF, bf16* __restrict__ outB,
                          int causal)
{
    __shared__ alignas(16) bf16 Ks[64][72];      // [key][d]
    __shared__ alignas(16) bf16 Vt[64][72];      // [d][key]
    __shared__ alignas(16) bf16 Ps[4][16][72];   // per-wave [q][key]

    const int t = threadIdx.x;
    const int w = t >> 6;
    const int lane = t & 63;
    const int r16 = lane & 15;
    const int quad = lane >> 4;
    const int bh = blockIdx.y;
    const int b = bh >> 3, h = bh & 7;
    const int q0 = blockIdx.x * 64;
    const size_t rowbase = (size_t)b * S_LEN;
    const int hoff = h * DKH;

    bf16x8 qf[2];
    {
        const bf16* qp = Qh + (rowbase + q0 + 16 * w + r16) * DMODEL + hoff + 8 * quad;
        qf[0] = *(const bf16x8*)(qp);
        qf[1] = *(const bf16x8*)(qp + 32);
    }

    floatx4 o[4];
#pragma unroll
    for (int dt = 0; dt < 4; dt++)
#pragma unroll
        for (int e = 0; e < 4; e++) o[dt][e] = 0.0f;
    float m = -3e38f, l = 0.0f;

    const int nchunk = causal ? (q0 / 64 + 1) : (S_LEN / 64);
    const int rr0 = t >> 3;
    const int cc = (t & 7) * 8;

    for (int ch = 0; ch < nchunk; ch++) {
        const int kb = ch * 64;
        __syncthreads();
        {
#pragma unroll
            for (int p = 0; p < 2; p++) {
                const int row = rr0 + 32 * p;
                const size_t goff = (rowbase + kb + row) * DMODEL + hoff + cc;
                *(uint4*)&Ks[row][cc] = *(const uint4*)(Kh + goff);
                union { uint4 u; bf16 hh[8]; } vv;
                vv.u = *(const uint4*)(Vh + goff);
#pragma unroll
                for (int j = 0; j < 8; j++) Vt[cc + j][row] = vv.hh[j];
            }
        }
        __syncthreads();

        floatx4 sacc[4];
#pragma unroll
        for (int i = 0; i < 4; i++)
#pragma unroll
            for (int e = 0; e < 4; e++) sacc[i][e] = 0.0f;
#pragma unroll
        for (int t2 = 0; t2 < 2; t2++) {
            bf16x8 kf[4];
#pragma unroll
            for (int i = 0; i < 4; i++)
                kf[i] = *(const bf16x8*)&Ks[16 * i + r16][32 * t2 + 8 * quad];
#pragma unroll
            for (int i = 0; i < 4; i++)
                sacc[i] = __builtin_amdgcn_mfma_f32_16x16x32_bf16(kf[i], qf[t2], sacc[i], 0, 0, 0);
        }

        const int qg = q0 + 16 * w + r16;
        float mc = -3e38f;
#pragma unroll
        for (int i = 0; i < 4; i++)
#pragma unroll
            for (int e = 0; e < 4; e++) {
                float sv = sacc[i][e] * 0.125f;
                if (causal && (kb + 16 * i + 4 * quad + e > qg)) sv = -3e38f;
                sacc[i][e] = sv;
                mc = fmaxf(mc, sv);
            }
        mc = fmaxf(mc, __shfl_xor(mc, 16, 64));
        mc = fmaxf(mc, __shfl_xor(mc, 32, 64));
        const float mn = fmaxf(m, mc);
        const float alpha = __expf(m - mn);
        m = mn;

        float lc = 0.0f;
#pragma unroll
        for (int i = 0; i < 4; i++) {
            float p0 = __expf(sacc[i][0] - mn);
            float p1 = __expf(sacc[i][1] - mn);
            float p2 = __expf(sacc[i][2] - mn);
            float p3 = __expf(sacc[i][3] - mn);
            lc += (p0 + p1) + (p2 + p3);
            uint2 pw;
            pw.x = pack2bf(p0, p1);
            pw.y = pack2bf(p2, p3);
            *(uint2*)&Ps[w][r16][16 * i + 4 * quad] = pw;
        }
        lc += __shfl_xor(lc, 16, 64);
        lc += __shfl_xor(lc, 32, 64);
        l = l * alpha + lc;

        float aq[4];
#pragma unroll
        for (int e = 0; e < 4; e++) aq[e] = __shfl(alpha, 4 * quad + e, 64);
#pragma unroll
        for (int dt = 0; dt < 4; dt++)
#pragma unroll
            for (int e = 0; e < 4; e++) o[dt][e] *= aq[e];

#pragma unroll
        for (int t2 = 0; t2 < 2; t2++) {
            const bf16x8 pf = *(const bf16x8*)&Ps[w][r16][32 * t2 + 8 * quad];
#pragma unroll
            for (int dt = 0; dt < 4; dt++) {
                const bf16x8 vf = *(const bf16x8*)&Vt[16 * dt + r16][32 * t2 + 8 * quad];
                o[dt] = __builtin_amdgcn_mfma_f32_16x16x32_bf16(pf, vf, o[dt], 0, 0, 0);
            }
        }
    }

    float linv[4];
#pragma unroll
    for (int e = 0; e < 4; e++) linv[e] = 1.0f / __shfl(l, 4 * quad + e, 64);
#pragma unroll
    for (int dt = 0; dt < 4; dt++)
#pragma unroll
        for (int e = 0; e < 4; e++) {
            const float v = o[dt][e] * linv[e];
            const size_t idx = (rowbase + q0 + 16 * w + 4 * quad + e) * DMODEL
                             + hoff + 16 * dt + r16;
            if (outF) outF[idx] = v;
            if (outB) outB[idx] = __float2bfloat16(v);
        }
}

// ---------------------------------------------------------------------------
// Fused residual + LayerNorm over D=512. One WG (256 thr) per row.
// ---------------------------------------------------------------------------
__launch_bounds__(256)
__global__ void ln_kernel(const float* __restrict__ xmain,
                          const float* __restrict__ resF, const bf16* __restrict__ resB,
                          const float* __restrict__ g, const float* __restrict__ bb,
                          float* __restrict__ outF, bf16* __restrict__ outB)
{
    const int row = blockIdx.x;
    const int t = threadIdx.x;
    const size_t base = (size_t)row * DMODEL;

    float x0 = xmain[base + t];
    float x1 = xmain[base + t + 256];
    if (resF) { x0 += resF[base + t]; x1 += resF[base + t + 256]; }
    if (resB) { x0 += __bfloat162float(resB[base + t]); x1 += __bfloat162float(resB[base + t + 256]); }

    __shared__ float sred[4];
    float s = x0 + x1;
#pragma unroll
    for (int off = 32; off > 0; off >>= 1) s += __shfl_down(s, off);
    if ((t & 63) == 0) sred[t >> 6] = s;
    __syncthreads();
    const float mu = (sred[0] + sred[1] + sred[2] + sred[3]) * (1.0f / DMODEL);

    const float d0 = x0 - mu, d1 = x1 - mu;
    float sv = d0 * d0 + d1 * d1;
#pragma unroll
    for (int off = 32; off > 0; off >>= 1) sv += __shfl_down(sv, off);
    __syncthreads();
    if ((t & 63) == 0) sred[t >> 6] = sv;
    __syncthreads();
    const float var = (sred[0] + sred[1] + sred[2] + sred[3]) * (1.0f / DMODEL);
    const float rstd = rsqrtf(var + 1e-5f);

    const float y0 = d0 * rstd * g[t] + bb[t];
    const float y1 = d1 * rstd * g[t + 256] + bb[t + 256];
    if (outF) { outF[base + t] = y0; outF[base + t + 256] = y1; }
    if (outB) { outB[base + t] = __float2bfloat16(y0); outB[base + t + 256] = __float2bfloat16(y1); }
}

// ---------------------------------------------------------------------------
// Workspace layout (55.5 MB):
//   [ 0, 4)MB  q16      } h16 (16 MB) aliases [0,16) during FFN
//   [ 4, 8)MB  k16
//   [ 8,12)MB  v16
//   [12,16)MB  a16
//   [16,24)MB  tmp   fp32 (pre-LN main term)
//   [24,28)MB  y16  / [28,32) ya16 / [32,36) ya2
//   [36,48)MB  xq16 / x1_16 / x2_16 (bf16 copies of the fp32 inputs)
//   [48,55.5)MB bf16 weights: sa_wq,sa_wk,sa_wv (512K ea), mha_in_w (1.5M),
//               mha_out_w (512K), ffn_w1 (2M), ffn_w2 (2M)
// ---------------------------------------------------------------------------
extern "C" void kernel_launch(void* const* d_in, const int* in_sizes, int n_in,
                              void* d_out, int out_size, void* d_ws, size_t ws_size,
                              hipStream_t stream)
{
    // ALL inputs are float32 per the reference.
    const float* x_q       = (const float*)d_in[0];
    const float* x1        = (const float*)d_in[1];
    const float* x2        = (const float*)d_in[2];
    const float* sa_wq     = (const float*)d_in[3];
    const float* sa_bq     = (const float*)d_in[4];
    const float* sa_wk     = (const float*)d_in[5];
    const float* sa_bk     = (const float*)d_in[6];
    const float* sa_wv     = (const float*)d_in[7];
    const float* sa_bv     = (const float*)d_in[8];
    const float* ln1_g     = (const float*)d_in[9];
    const float* ln1_b     = (const float*)d_in[10];
    const float* mha_in_w  = (const float*)d_in[11];
    const float* mha_in_b  = (const float*)d_in[12];
    const float* mha_out_w = (const float*)d_in[13];
    const float* mha_out_b = (const float*)d_in[14];
    const float* ln2_g     = (const float*)d_in[15];
    const float* ln2_b     = (const float*)d_in[16];
    const float* ffn_w1    = (const float*)d_in[17];
    const float* ffn_b1    = (const float*)d_in[18];
    const float* ffn_w2    = (const float*)d_in[19];
    const float* ffn_b2    = (const float*)d_in[20];
    const float* ln3_g     = (const float*)d_in[21];
    const float* ln3_b     = (const float*)d_in[22];

    char* ws = (char*)d_ws;
    const size_t MB = 1024 * 1024;
    const size_t KB = 1024;
    bf16*  q16  = (bf16*)(ws + 0 * MB);
    bf16*  k16  = (bf16*)(ws + 4 * MB);
    bf16*  v16  = (bf16*)(ws + 8 * MB);
    bf16*  a16  = (bf16*)(ws + 12 * MB);
    float* tmp  = (float*)(ws + 16 * MB);
    bf16*  y16  = (bf16*)(ws + 24 * MB);
    bf16*  ya16 = (bf16*)(ws + 28 * MB);
    bf16*  ya2  = (bf16*)(ws + 32 * MB);
    bf16*  xq16 = (bf16*)(ws + 36 * MB);
    bf16*  x116 = (bf16*)(ws + 40 * MB);
    bf16*  x216 = (bf16*)(ws + 44 * MB);
    bf16*  w_sa_q = (bf16*)(ws + 48 * MB);
    bf16*  w_sa_k = (bf16*)(ws + 48 * MB + 512 * KB);
    bf16*  w_sa_v = (bf16*)(ws + 49 * MB);
    bf16*  w_in   = (bf16*)(ws + 49 * MB + 512 * KB);   // 1.5 MB (3D x D)
    bf16*  w_out  = (bf16*)(ws + 51 * MB);              // 0.5 MB
    bf16*  w_f1   = (bf16*)(ws + 51 * MB + 512 * KB);   // 2 MB
    bf16*  w_f2   = (bf16*)(ws + 53 * MB + 512 * KB);   // 2 MB
    bf16*  h16    = (bf16*)(ws + 0 * MB);               // aliases q..a (dead by FFN)

    // ---- one-shot fp32 -> bf16 conversions ----
    const int DD = DMODEL * DMODEL;       // 262144
    CvtDesc cd;
    cd.seg[0]  = { x_q,       xq16,   (NROWS * DMODEL) / 4 };
    cd.seg[1]  = { x1,        x116,   (NROWS * DMODEL) / 4 };
    cd.seg[2]  = { x2,        x216,   (NROWS * DMODEL) / 4 };
    cd.seg[3]  = { sa_wq,     w_sa_q, DD / 4 };
    cd.seg[4]  = { sa_wk,     w_sa_k, DD / 4 };
    cd.seg[5]  = { sa_wv,     w_sa_v, DD / 4 };
    cd.seg[6]  = { mha_in_w,  w_in,   3 * DD / 4 };
    cd.seg[7]  = { mha_out_w, w_out,  DD / 4 };
    cd.seg[8]  = { ffn_w1,    w_f1,   (FFDIM * DMODEL) / 4 };
    cd.seg[9]  = { ffn_w2,    w_f2,   (FFDIM * DMODEL) / 4 };
    cd.seg[10] = { x_q,       xq16,   0 };   // padding (inactive)
    cd.seg[11] = { x_q,       xq16,   0 };
    cvt_f32_bf16<<<dim3(64, 10), 256, 0, stream>>>(cd);

    const dim3 blk(256);
    const dim3 g512(NROWS / 128, DMODEL / 64);   // (32, 8) = 256 blocks
    const dim3 gFF1(NROWS / 128, FFDIM / 128);   // (32,16) = 512 blocks
    const dim3 agrid(S_LEN / 64, BATCH * NHEAD); // (32,16)

    // ---- self attention (causal, no out-proj) ----
    gemm_lds<128, 64, false><<<g512, blk, 0, stream>>>(xq16, w_sa_q, sa_bq, nullptr, q16, DMODEL, DMODEL);
    gemm_lds<128, 64, false><<<g512, blk, 0, stream>>>(xq16, w_sa_k, sa_bk, nullptr, k16, DMODEL, DMODEL);
    gemm_lds<128, 64, false><<<g512, blk, 0, stream>>>(xq16, w_sa_v, sa_bv, nullptr, v16, DMODEL, DMODEL);
    attn_mfma<<<agrid, blk, 0, stream>>>(q16, k16, v16, tmp, nullptr, 1);
    ln_kernel<<<NROWS, blk, 0, stream>>>(tmp, x_q, nullptr, ln1_g, ln1_b, nullptr, y16);

    // ---- cross attention 1: q from y, k/v from x1 ----
    gemm_lds<128, 64, false><<<g512, blk, 0, stream>>>(y16, w_in, mha_in_b, nullptr, q16, DMODEL, DMODEL);
    gemm_lds<128, 64, false><<<g512, blk, 0, stream>>>(x116, w_in + (size_t)DD, mha_in_b + DMODEL, nullptr, k16, DMODEL, DMODEL);
    gemm_lds<128, 64, false><<<g512, blk, 0, stream>>>(x116, w_in + (size_t)2 * DD, mha_in_b + 2 * DMODEL, nullptr, v16, DMODEL, DMODEL);
    attn_mfma<<<agrid, blk, 0, stream>>>(q16, k16, v16, nullptr, a16, 0);
    gemm_lds<128, 64, false><<<g512, blk, 0, stream>>>(a16, w_out, mha_out_b, tmp, nullptr, DMODEL, DMODEL);
    ln_kernel<<<NROWS, blk, 0, stream>>>(tmp, nullptr, y16, ln2_g, ln2_b, nullptr, ya16);

    // ---- cross attention 2: q from yattn, k/v from x2 ----
    gemm_lds<128, 64, false><<<g512, blk, 0, stream>>>(ya16, w_in, mha_in_b, nullptr, q16, DMODEL, DMODEL);
    gemm_lds<128, 64, false><<<g512, blk, 0, stream>>>(x216, w_in + (size_t)DD, mha_in_b + DMODEL, nullptr, k16, DMODEL, DMODEL);
    gemm_lds<128, 64, false><<<g512, blk, 0, stream>>>(x216, w_in + (size_t)2 * DD, mha_in_b + 2 * DMODEL, nullptr, v16, DMODEL, DMODEL);
    attn_mfma<<<agrid, blk, 0, stream>>>(q16, k16, v16, nullptr, a16, 0);
    gemm_lds<128, 64, false><<<g512, blk, 0, stream>>>(a16, w_out, mha_out_b, tmp, nullptr, DMODEL, DMODEL);
    ln_kernel<<<NROWS, blk, 0, stream>>>(tmp, nullptr, ya16, ln2_g, ln2_b, nullptr, ya2);

    // ---- FFN ----
    gemm_lds<128, 128, true ><<<gFF1, blk, 0, stream>>>(ya2, w_f1, ffn_b1, nullptr, h16, FFDIM, DMODEL);
    gemm_lds<128, 64, false><<<g512, blk, 0, stream>>>(h16, w_f2, ffn_b2, tmp, nullptr, DMODEL, FFDIM);
    ln_kernel<<<NROWS, blk, 0, stream>>>(tmp, nullptr, ya2, ln3_g, ln3_b, (float*)d_out, nullptr);
}